// Round 21
// baseline (151.293 us; speedup 1.0000x reference)
//
#include <hip/hip_runtime.h>

typedef __attribute__((ext_vector_type(8))) _Float16 h8v;  // 8 fp16 (4 VGPR)
typedef __attribute__((ext_vector_type(4))) float    f4v;  // MFMA accumulator

#define N_   4096
#define N2   8192
#define D_   256
#define NIDS 1000
#define LCAP 32

constexpr float INV_TEMP = 10.0f;                 // 1/0.1
constexpr float K_LOG2   = 14.426950408889634f;   // 10 * log2(e)
constexpr float LN2F     = 0.6931471805599453f;
constexpr float NEGINF   = -1e30f;

__device__ __forceinline__ const float* frow(const float* f, int r) {
    return f + (size_t)(r & (N_ - 1)) * (2 * D_) + (size_t)((r >> 12) * D_);
}

// convert 8 f32 -> 8 fp16, one ds_write_b128
__device__ __forceinline__ void wr16(void* p, float4 x, float4 y) {
    h8v h;
    h[0] = (_Float16)x.x; h[1] = (_Float16)x.y; h[2] = (_Float16)x.z; h[3] = (_Float16)x.w;
    h[4] = (_Float16)y.x; h[5] = (_Float16)y.y; h[6] = (_Float16)y.z; h[7] = (_Float16)y.w;
    *(h8v*)p = h;
}

// ---------- Phase A': lists (blocks<250) + upper-tri 128x128 fp16 tile with ----------
// ---------- inline f32->fp16 reg-staged staging. 5 blocks/CU (64 VGPR, 32KB) ----------
__global__ __launch_bounds__(256, 5) void phaseA(const float* __restrict__ feat,
                                                 const int* __restrict__ label,
                                                 float2* __restrict__ partial,
                                                 int* __restrict__ lists,
                                                 int* __restrict__ done) {
    __shared__ char lds[32768];   // 2 buf x (A 8KB | B 8KB)

    const int tid  = threadIdx.x;
    const int lane = tid & 63;
    const int w    = tid >> 6;
    const int wr   = w >> 1, wc = w & 1;
    const int l15  = lane & 15;

    if (blockIdx.x == 0 && tid == 0) *done = 0;   // reset phaseB ticket every call

    // ---- class lists (250 blocks x 4 waves = 1000 classes), before tile work ----
    if (blockIdx.x < 250) {
        int cls = blockIdx.x * 4 + w;
        int* Lp = lists + (size_t)cls * (LCAP + 1);
        int cnt = 0;
        for (int jj = 0; jj < N_; jj += 64) {
            unsigned long long mk = __ballot(label[jj + lane] == cls);
            while (mk) {
                int b = __ffsll((unsigned long long)mk) - 1;
                mk &= mk - 1;
                if (lane == 0 && cnt < LCAP) Lp[1 + cnt] = jj + b;
                ++cnt;
            }
        }
        if (lane == 0) Lp[0] = (cnt < LCAP) ? cnt : LCAP;
    }

    // ---- tile decode: XCD swizzle (2080 = 8*260, bijective) + upper-tri ----
    int idx = (blockIdx.x & 7) * 260 + (blockIdx.x >> 3);
    int rt = 0, rem = idx;
    while (rem >= 64 - rt) { rem -= 64 - rt; ++rt; }
    const int ct = rt + rem;
    const bool offdiag = (ct != rt);
    const int rowBase = rt * 128, colBase = ct * 128;

    f4v acc[4][4];
    #pragma unroll
    for (int i = 0; i < 4; ++i)
        #pragma unroll
        for (int j = 0; j < 4; ++j) acc[i][j] = (f4v){0.f, 0.f, 0.f, 0.f};

    // staging geometry: lane l writes LDS[row = l>>2 (+16i)][slot = l&3]
    // from G[row][slot ^ ((row>>1)&3)]  (16B-granular XOR swizzle)
    const int prB  = (w < 2) ? rowBase : colBase;
    const int ssrc = (lane & 3) ^ ((lane >> 3) & 3);
    const int r0   = prB + (w & 1) * 64 + (lane >> 2);
    const float* rp[4];
    #pragma unroll
    for (int i = 0; i < 4; ++i) rp[i] = frow(feat, r0 + 16 * i) + ssrc * 8;
    const int ldoff = ((w >= 2) ? 8192 : 0) + (w & 1) * 4096 + lane * 16;

    // prologue: chunk 0 -> buf 0
    {
        float4 t0 = *(const float4*)(rp[0]),     t1 = *(const float4*)(rp[0] + 4);
        float4 t2 = *(const float4*)(rp[1]),     t3 = *(const float4*)(rp[1] + 4);
        wr16(lds + ldoff,        t0, t1);
        wr16(lds + ldoff + 1024, t2, t3);
        t0 = *(const float4*)(rp[2]);  t1 = *(const float4*)(rp[2] + 4);
        t2 = *(const float4*)(rp[3]);  t3 = *(const float4*)(rp[3] + 4);
        wr16(lds + ldoff + 2048, t0, t1);
        wr16(lds + ldoff + 3072, t2, t3);
    }

    const int phys  = ((lane >> 4) ^ ((l15 >> 1) & 3)) * 16;
    const int aoff0 = (wr * 64 + l15) * 64 + phys;
    const int boff0 = 8192 + (wc * 64 + l15) * 64 + phys;

    // K-loop: one barrier per chunk. Top barrier makes prev writes (buf[cur])
    // visible AND separates prev reads of buf[cur^1] from this iter's writes.
    for (int kc = 0; kc < 8; ++kc) {
        const int cur = kc & 1;
        __syncthreads();
        const char* bb = lds + cur * 16384;
        char* wp = lds + (cur ^ 1) * 16384 + ldoff;
        const bool st = (kc < 7);
        const int kB = (kc + 1) * 32;

        float4 t0, t1, t2, t3;
        if (st) {   // rows 0,1 of next chunk: issue early, land under MFMAs
            t0 = *(const float4*)(rp[0] + kB); t1 = *(const float4*)(rp[0] + kB + 4);
            t2 = *(const float4*)(rp[1] + kB); t3 = *(const float4*)(rp[1] + kB + 4);
        }

        h8v a0 = *(const h8v*)(bb + aoff0);
        h8v a1 = *(const h8v*)(bb + aoff0 + 1024);
        h8v a2 = *(const h8v*)(bb + aoff0 + 2048);
        h8v a3 = *(const h8v*)(bb + aoff0 + 3072);

        {
            h8v b = *(const h8v*)(bb + boff0);
            acc[0][0] = __builtin_amdgcn_mfma_f32_16x16x32_f16(a0, b, acc[0][0], 0, 0, 0);
            acc[1][0] = __builtin_amdgcn_mfma_f32_16x16x32_f16(a1, b, acc[1][0], 0, 0, 0);
            acc[2][0] = __builtin_amdgcn_mfma_f32_16x16x32_f16(a2, b, acc[2][0], 0, 0, 0);
            acc[3][0] = __builtin_amdgcn_mfma_f32_16x16x32_f16(a3, b, acc[3][0], 0, 0, 0);
        }
        {
            h8v b = *(const h8v*)(bb + boff0 + 1024);
            acc[0][1] = __builtin_amdgcn_mfma_f32_16x16x32_f16(a0, b, acc[0][1], 0, 0, 0);
            acc[1][1] = __builtin_amdgcn_mfma_f32_16x16x32_f16(a1, b, acc[1][1], 0, 0, 0);
            acc[2][1] = __builtin_amdgcn_mfma_f32_16x16x32_f16(a2, b, acc[2][1], 0, 0, 0);
            acc[3][1] = __builtin_amdgcn_mfma_f32_16x16x32_f16(a3, b, acc[3][1], 0, 0, 0);
        }

        if (st) {   // write rows 0,1; then issue rows 2,3 loads
            wr16(wp,        t0, t1);
            wr16(wp + 1024, t2, t3);
            t0 = *(const float4*)(rp[2] + kB); t1 = *(const float4*)(rp[2] + kB + 4);
            t2 = *(const float4*)(rp[3] + kB); t3 = *(const float4*)(rp[3] + kB + 4);
        }

        {
            h8v b = *(const h8v*)(bb + boff0 + 2048);
            acc[0][2] = __builtin_amdgcn_mfma_f32_16x16x32_f16(a0, b, acc[0][2], 0, 0, 0);
            acc[1][2] = __builtin_amdgcn_mfma_f32_16x16x32_f16(a1, b, acc[1][2], 0, 0, 0);
            acc[2][2] = __builtin_amdgcn_mfma_f32_16x16x32_f16(a2, b, acc[2][2], 0, 0, 0);
            acc[3][2] = __builtin_amdgcn_mfma_f32_16x16x32_f16(a3, b, acc[3][2], 0, 0, 0);
        }
        {
            h8v b = *(const h8v*)(bb + boff0 + 3072);
            acc[0][3] = __builtin_amdgcn_mfma_f32_16x16x32_f16(a0, b, acc[0][3], 0, 0, 0);
            acc[1][3] = __builtin_amdgcn_mfma_f32_16x16x32_f16(a1, b, acc[1][3], 0, 0, 0);
            acc[2][3] = __builtin_amdgcn_mfma_f32_16x16x32_f16(a2, b, acc[2][3], 0, 0, 0);
            acc[3][3] = __builtin_amdgcn_mfma_f32_16x16x32_f16(a3, b, acc[3][3], 0, 0, 0);
        }

        if (st) {
            wr16(wp + 2048, t0, t1);
            wr16(wp + 3072, t2, t3);
        }
    }
    __syncthreads();   // all waves' LDS reads done before epilogue reuse

    // ================= epilogue (log2 domain), LDS reused ==================
    float* rowm  = (float*)lds;              // [128][33]  (16896 B)
    float* colm  = (float*)(lds + 16896);    // [128][9]   (4608 B)
    float* mrowS = (float*)(lds + 21504);    // [128]
    float* mcolS = (float*)(lds + 22016);    // [128]

    const int grp32 = wc * 16 + l15;
    const int grp8  = wr * 4 + (lane >> 4);
    int rloc[16], cloc[4];
    int rowlab[16], collab[4];
    #pragma unroll
    for (int rf = 0; rf < 4; ++rf)
        #pragma unroll
        for (int rg = 0; rg < 4; ++rg) {
            int i = rf * 4 + rg;
            rloc[i] = wr * 64 + rf * 16 + (lane >> 4) * 4 + rg;
            rowlab[i] = label[(rowBase + rloc[i]) & (N_ - 1)];
        }
    #pragma unroll
    for (int cf = 0; cf < 4; ++cf) {
        cloc[cf] = wc * 64 + cf * 16 + l15;
        collab[cf] = label[(colBase + cloc[cf]) & (N_ - 1)];
    }

    // masked log2-logits in place
    #pragma unroll
    for (int rf = 0; rf < 4; ++rf)
        #pragma unroll
        for (int cf = 0; cf < 4; ++cf)
            #pragma unroll
            for (int rg = 0; rg < 4; ++rg) {
                float v = acc[rf][cf][rg] * K_LOG2;
                acc[rf][cf][rg] = (collab[cf] == rowlab[rf * 4 + rg]) ? NEGINF : v;
            }

    // pass 1: maxes
    #pragma unroll
    for (int rf = 0; rf < 4; ++rf)
        #pragma unroll
        for (int rg = 0; rg < 4; ++rg) {
            float m = fmaxf(fmaxf(acc[rf][0][rg], acc[rf][1][rg]),
                            fmaxf(acc[rf][2][rg], acc[rf][3][rg]));
            rowm[rloc[rf * 4 + rg] * 33 + grp32] = m;
        }
    if (offdiag) {
        #pragma unroll
        for (int cf = 0; cf < 4; ++cf) {
            float m = NEGINF;
            #pragma unroll
            for (int rf = 0; rf < 4; ++rf)
                #pragma unroll
                for (int rg = 0; rg < 4; ++rg) m = fmaxf(m, acc[rf][cf][rg]);
            colm[cloc[cf] * 9 + grp8] = m;
        }
    }
    __syncthreads();
    if (tid < 128) {
        float m = NEGINF;
        #pragma unroll
        for (int g = 0; g < 32; ++g) m = fmaxf(m, rowm[tid * 33 + g]);
        mrowS[tid] = m;
        if (offdiag) {
            float mc = NEGINF;
            #pragma unroll
            for (int g = 0; g < 8; ++g) mc = fmaxf(mc, colm[tid * 9 + g]);
            mcolS[tid] = mc;
        }
    }
    __syncthreads();

    // pass 2: sums (reuse rowm/colm)
    #pragma unroll
    for (int rf = 0; rf < 4; ++rf)
        #pragma unroll
        for (int rg = 0; rg < 4; ++rg) {
            int i = rf * 4 + rg;
            float m = mrowS[rloc[i]];
            float s = 0.f;
            #pragma unroll
            for (int cf = 0; cf < 4; ++cf) s += exp2f(acc[rf][cf][rg] - m);
            rowm[rloc[i] * 33 + grp32] = s;
        }
    if (offdiag) {
        #pragma unroll
        for (int cf = 0; cf < 4; ++cf) {
            float m = mcolS[cloc[cf]];
            float s = 0.f;
            #pragma unroll
            for (int rf = 0; rf < 4; ++rf)
                #pragma unroll
                for (int rg = 0; rg < 4; ++rg) s += exp2f(acc[rf][cf][rg] - m);
            colm[cloc[cf] * 9 + grp8] = s;
        }
    }
    __syncthreads();
    if (tid < 128) {
        float s = 0.f;
        #pragma unroll
        for (int g = 0; g < 32; ++g) s += rowm[tid * 33 + g];
        partial[(size_t)(rowBase + tid) * 64 + ct] = make_float2(mrowS[tid], s);
        if (offdiag) {
            float s2 = 0.f;
            #pragma unroll
            for (int g = 0; g < 8; ++g) s2 += colm[tid * 9 + g];
            partial[(size_t)(colBase + tid) * 64 + rt] = make_float2(mcolS[tid], s2);
        }
    }
}

// ---------- Phase B: merge + group-parallel dots + CE + last-block final ----------
__global__ __launch_bounds__(512) void phaseB(const float* __restrict__ feat,
                                              const int* __restrict__ label,
                                              const int* __restrict__ camid,
                                              const int* __restrict__ lists,
                                              const float2* __restrict__ partial,
                                              float* __restrict__ rowloss,
                                              int* __restrict__ done,
                                              float* __restrict__ out) {
    __shared__ int   cList[8][64];
    __shared__ int   fList[8][64];
    __shared__ float pList[8][64];
    __shared__ float red[512];
    __shared__ int   lastFlag;

    const int tid = threadIdx.x, lane = tid & 63, w = tid >> 6;
    const int row = blockIdx.x * 8 + w;
    const int rl = label[row & (N_ - 1)];
    const int rc = camid[row & (N_ - 1)];

    // c_id: coalesced row-major partial + butterfly merge (log2 domain)
    float2 p = partial[(size_t)row * 64 + lane];
    float mm = p.x, ms = p.y;
    #pragma unroll
    for (int off = 32; off >= 1; off >>= 1) {
        float om = __shfl_xor(mm, off), os = __shfl_xor(ms, off);
        float nm = fmaxf(mm, om);
        ms = ms * exp2f(mm - nm) + os * exp2f(om - nm);
        mm = nm;
    }
    const float cid = (mm + __log2f(ms)) * LN2F;

    // own row slice: lane li=lane&15 covers floats [li*16, li*16+16)
    const int li = lane & 15, g = lane >> 4;
    const float4* fip = (const float4*)frow(feat, row);
    float4 fiv[4];
    #pragma unroll
    for (int k = 0; k < 4; ++k) fiv[k] = fip[li * 4 + k];

    // candidate compaction (ascending, deterministic)
    const int* Lp = lists + (size_t)rl * (LCAP + 1);
    const int nmem = Lp[0];
    int jm = (lane < 2 * nmem) ? Lp[1 + (lane >> 1)] : -1;
    int cand = jm + (lane & 1) * N_;
    bool valid = (jm >= 0) && (cand != row);
    unsigned long long mask = __ballot(valid);
    int cnt = __popcll(mask);
    int pos = __popcll(mask & ((1ull << lane) - 1ull));
    if (valid) {
        cList[w][pos] = cand;
        fList[w][pos] = (camid[jm] == rc) ? 1 : 0;
    }

    // group-parallel dots: 4 candidates per batch (16 lanes each)
    const int nb = (cnt + 3) >> 2;
    for (int b = 0; b < nb; ++b) {
        int e = b * 4 + g;
        bool act = (e < cnt);
        int c = act ? cList[w][e] : row;
        const float4* fcp = (const float4*)frow(feat, c);
        float pp = 0.f;
        #pragma unroll
        for (int k = 0; k < 4; ++k) {
            float4 v = fcp[li * 4 + k];
            pp += fiv[k].x * v.x + fiv[k].y * v.y + fiv[k].z * v.z + fiv[k].w * v.w;
        }
        #pragma unroll
        for (int off = 8; off >= 1; off >>= 1) pp += __shfl_xor(pp, off);
        if (act && li == 0) pList[w][e] = pp * INV_TEMP;
    }

    float a_e = (lane < cnt) ? pList[w][lane] : NEGINF;
    int   f_e = (lane < cnt) ? fList[w][lane] : 1;

    // extras LSE (label-match, cam-mismatch) -> c_cam
    float xa = (f_e == 0) ? a_e : NEGINF;
    float mx = xa;
    #pragma unroll
    for (int off = 32; off >= 1; off >>= 1) mx = fmaxf(mx, __shfl_xor(mx, off));
    float xe = (f_e == 0) ? __expf(xa - mx) : 0.f;
    #pragma unroll
    for (int off = 32; off >= 1; off >>= 1) xe += __shfl_xor(xe, off);
    float ccam;
    if (xe > 0.f) {
        float xl = mx + __logf(xe);
        float d = xl - cid;
        ccam = (d <= 0.f) ? cid + log1pf(__expf(d)) : xl + log1pf(__expf(-d));
    } else {
        ccam = cid;
    }

    float ti = cid - a_e;
    float termid = (ti <= 0.f) ? log1pf(__expf(ti)) : ti + log1pf(__expf(-ti));
    termid = (lane < cnt) ? termid : 0.f;
    float tc = ccam - a_e;
    float termcam = (tc <= 0.f) ? log1pf(__expf(tc)) : tc + log1pf(__expf(-tc));
    termcam = (lane < cnt && f_e) ? termcam : 0.f;
    #pragma unroll
    for (int off = 32; off >= 1; off >>= 1) {
        termid  += __shfl_xor(termid, off);
        termcam += __shfl_xor(termcam, off);
    }
    int ncam = __popcll(__ballot(lane < cnt && f_e));
    if (lane == 0)
        rowloss[row] = termid / (float)cnt + 0.5f * termcam / (float)ncam;

    // ---- last-block deterministic final reduce ----
    __syncthreads();
    if (tid == 0) {
        __threadfence();
        lastFlag = (atomicAdd(done, 1) == (int)gridDim.x - 1) ? 1 : 0;
    }
    __syncthreads();
    if (lastFlag) {
        __threadfence();
        float s = 0.f;
        const int b0 = tid * 16;
        #pragma unroll
        for (int i = 0; i < 16; ++i) s += rowloss[b0 + i];   // fixed order
        red[tid] = s;
        __syncthreads();
        for (int ww = 256; ww > 0; ww >>= 1) {
            if (tid < ww) red[tid] += red[tid + ww];
            __syncthreads();
        }
        if (tid == 0) out[0] = red[0] / (float)N2;
    }
}

extern "C" void kernel_launch(void* const* d_in, const int* in_sizes, int n_in,
                              void* d_out, int out_size, void* d_ws, size_t ws_size,
                              hipStream_t stream) {
    const float* feat  = (const float*)d_in[0];
    const int*   label = (const int*)d_in[1];
    const int*   camid = (const int*)d_in[2];

    float2* partial = (float2*)d_ws;                                 // 4 MB
    float*  rowloss = (float*)((char*)d_ws + 4u * 1024 * 1024);      // 32 KB
    int*    lists   = (int*)(rowloss + N2);                          // ~132 KB
    int*    done    = lists + NIDS * (LCAP + 1);                     // 4 B

    phaseA<<<2080, 256, 0, stream>>>(feat, label, partial, lists, done);
    phaseB<<<1024, 512, 0, stream>>>(feat, label, camid, lists, partial,
                                     rowloss, done, (float*)d_out);
}

// Round 22
// 93.168 us; speedup vs baseline: 1.6239x; 1.6239x over previous
//
#include <hip/hip_runtime.h>

typedef __attribute__((ext_vector_type(8))) _Float16 h8v;  // 8 fp16 (4 VGPR)
typedef __attribute__((ext_vector_type(4))) float    f4v;  // MFMA accumulator

#define N_   4096
#define N2   8192
#define D_   256
#define NIDS 1000
#define LCAP 32

constexpr float INV_TEMP = 10.0f;                 // 1/0.1
constexpr float K_LOG2   = 14.426950408889634f;   // 10 * log2(e)
constexpr float LN2F     = 0.6931471805599453f;
constexpr float NEGINF   = -1e30f;

__device__ __forceinline__ const float* frow(const float* f, int r) {
    return f + (size_t)(r & (N_ - 1)) * (2 * D_) + (size_t)((r >> 12) * D_);
}

// convert 8 f32 -> 8 fp16, one ds_write_b128
__device__ __forceinline__ void wr16(void* p, float4 x, float4 y) {
    h8v h;
    h[0] = (_Float16)x.x; h[1] = (_Float16)x.y; h[2] = (_Float16)x.z; h[3] = (_Float16)x.w;
    h[4] = (_Float16)y.x; h[5] = (_Float16)y.y; h[6] = (_Float16)y.z; h[7] = (_Float16)y.w;
    *(h8v*)p = h;
}

// ---------- Phase A': lists (blocks<250) + upper-tri 128x128 fp16 tile with ----------
// ---------- inline f32->fp16 reg-staged staging (4 blocks/CU: 5 spills!)    ----------
__global__ __launch_bounds__(256, 4) void phaseA(const float* __restrict__ feat,
                                                 const int* __restrict__ label,
                                                 float2* __restrict__ partial,
                                                 int* __restrict__ lists,
                                                 int* __restrict__ done) {
    __shared__ char lds[32768];   // 2 buf x (A 8KB | B 8KB)

    const int tid  = threadIdx.x;
    const int lane = tid & 63;
    const int w    = tid >> 6;
    const int wr   = w >> 1, wc = w & 1;
    const int l15  = lane & 15;

    if (blockIdx.x == 0 && tid == 0) *done = 0;   // reset phaseB ticket every call

    // ---- class lists (250 blocks x 4 waves = 1000 classes), before tile work ----
    if (blockIdx.x < 250) {
        int cls = blockIdx.x * 4 + w;
        int* Lp = lists + (size_t)cls * (LCAP + 1);
        int cnt = 0;
        for (int jj = 0; jj < N_; jj += 64) {
            unsigned long long mk = __ballot(label[jj + lane] == cls);
            while (mk) {
                int b = __ffsll((unsigned long long)mk) - 1;
                mk &= mk - 1;
                if (lane == 0 && cnt < LCAP) Lp[1 + cnt] = jj + b;
                ++cnt;
            }
        }
        if (lane == 0) Lp[0] = (cnt < LCAP) ? cnt : LCAP;
    }

    // ---- tile decode: XCD swizzle (2080 = 8*260, bijective) + upper-tri ----
    int idx = (blockIdx.x & 7) * 260 + (blockIdx.x >> 3);
    int rt = 0, rem = idx;
    while (rem >= 64 - rt) { rem -= 64 - rt; ++rt; }
    const int ct = rt + rem;
    const bool offdiag = (ct != rt);
    const int rowBase = rt * 128, colBase = ct * 128;

    f4v acc[4][4];
    #pragma unroll
    for (int i = 0; i < 4; ++i)
        #pragma unroll
        for (int j = 0; j < 4; ++j) acc[i][j] = (f4v){0.f, 0.f, 0.f, 0.f};

    // staging geometry: lane l writes LDS[row = l>>2 (+16i)][slot = l&3]
    // from G[row][slot ^ ((row>>1)&3)]  (16B-granular XOR swizzle)
    const int prB  = (w < 2) ? rowBase : colBase;
    const int ssrc = (lane & 3) ^ ((lane >> 3) & 3);
    const int r0   = prB + (w & 1) * 64 + (lane >> 2);
    const float* rp[4];
    #pragma unroll
    for (int i = 0; i < 4; ++i) rp[i] = frow(feat, r0 + 16 * i) + ssrc * 8;
    const int ldoff = ((w >= 2) ? 8192 : 0) + (w & 1) * 4096 + lane * 16;

    // prologue: chunk 0 -> buf 0
    {
        float4 t0 = *(const float4*)(rp[0]),     t1 = *(const float4*)(rp[0] + 4);
        float4 t2 = *(const float4*)(rp[1]),     t3 = *(const float4*)(rp[1] + 4);
        wr16(lds + ldoff,        t0, t1);
        wr16(lds + ldoff + 1024, t2, t3);
        t0 = *(const float4*)(rp[2]);  t1 = *(const float4*)(rp[2] + 4);
        t2 = *(const float4*)(rp[3]);  t3 = *(const float4*)(rp[3] + 4);
        wr16(lds + ldoff + 2048, t0, t1);
        wr16(lds + ldoff + 3072, t2, t3);
    }

    const int phys  = ((lane >> 4) ^ ((l15 >> 1) & 3)) * 16;
    const int aoff0 = (wr * 64 + l15) * 64 + phys;
    const int boff0 = 8192 + (wc * 64 + l15) * 64 + phys;

    // K-loop: one barrier per chunk. Top barrier makes prev writes (buf[cur])
    // visible AND separates prev reads of buf[cur^1] from this iter's writes.
    for (int kc = 0; kc < 8; ++kc) {
        const int cur = kc & 1;
        __syncthreads();
        const char* bb = lds + cur * 16384;
        char* wp = lds + (cur ^ 1) * 16384 + ldoff;
        const bool st = (kc < 7);
        const int kB = (kc + 1) * 32;

        float4 t0, t1, t2, t3;
        if (st) {   // rows 0,1 of next chunk: issue early, land under MFMAs
            t0 = *(const float4*)(rp[0] + kB); t1 = *(const float4*)(rp[0] + kB + 4);
            t2 = *(const float4*)(rp[1] + kB); t3 = *(const float4*)(rp[1] + kB + 4);
        }

        h8v a0 = *(const h8v*)(bb + aoff0);
        h8v a1 = *(const h8v*)(bb + aoff0 + 1024);
        h8v a2 = *(const h8v*)(bb + aoff0 + 2048);
        h8v a3 = *(const h8v*)(bb + aoff0 + 3072);

        {
            h8v b = *(const h8v*)(bb + boff0);
            acc[0][0] = __builtin_amdgcn_mfma_f32_16x16x32_f16(a0, b, acc[0][0], 0, 0, 0);
            acc[1][0] = __builtin_amdgcn_mfma_f32_16x16x32_f16(a1, b, acc[1][0], 0, 0, 0);
            acc[2][0] = __builtin_amdgcn_mfma_f32_16x16x32_f16(a2, b, acc[2][0], 0, 0, 0);
            acc[3][0] = __builtin_amdgcn_mfma_f32_16x16x32_f16(a3, b, acc[3][0], 0, 0, 0);
        }
        {
            h8v b = *(const h8v*)(bb + boff0 + 1024);
            acc[0][1] = __builtin_amdgcn_mfma_f32_16x16x32_f16(a0, b, acc[0][1], 0, 0, 0);
            acc[1][1] = __builtin_amdgcn_mfma_f32_16x16x32_f16(a1, b, acc[1][1], 0, 0, 0);
            acc[2][1] = __builtin_amdgcn_mfma_f32_16x16x32_f16(a2, b, acc[2][1], 0, 0, 0);
            acc[3][1] = __builtin_amdgcn_mfma_f32_16x16x32_f16(a3, b, acc[3][1], 0, 0, 0);
        }

        if (st) {   // write rows 0,1; then issue rows 2,3 loads
            wr16(wp,        t0, t1);
            wr16(wp + 1024, t2, t3);
            t0 = *(const float4*)(rp[2] + kB); t1 = *(const float4*)(rp[2] + kB + 4);
            t2 = *(const float4*)(rp[3] + kB); t3 = *(const float4*)(rp[3] + kB + 4);
        }

        {
            h8v b = *(const h8v*)(bb + boff0 + 2048);
            acc[0][2] = __builtin_amdgcn_mfma_f32_16x16x32_f16(a0, b, acc[0][2], 0, 0, 0);
            acc[1][2] = __builtin_amdgcn_mfma_f32_16x16x32_f16(a1, b, acc[1][2], 0, 0, 0);
            acc[2][2] = __builtin_amdgcn_mfma_f32_16x16x32_f16(a2, b, acc[2][2], 0, 0, 0);
            acc[3][2] = __builtin_amdgcn_mfma_f32_16x16x32_f16(a3, b, acc[3][2], 0, 0, 0);
        }
        {
            h8v b = *(const h8v*)(bb + boff0 + 3072);
            acc[0][3] = __builtin_amdgcn_mfma_f32_16x16x32_f16(a0, b, acc[0][3], 0, 0, 0);
            acc[1][3] = __builtin_amdgcn_mfma_f32_16x16x32_f16(a1, b, acc[1][3], 0, 0, 0);
            acc[2][3] = __builtin_amdgcn_mfma_f32_16x16x32_f16(a2, b, acc[2][3], 0, 0, 0);
            acc[3][3] = __builtin_amdgcn_mfma_f32_16x16x32_f16(a3, b, acc[3][3], 0, 0, 0);
        }

        if (st) {
            wr16(wp + 2048, t0, t1);
            wr16(wp + 3072, t2, t3);
        }
    }
    __syncthreads();   // all waves' LDS reads done before epilogue reuse

    // ================= epilogue (log2 domain), LDS reused ==================
    float* rowm  = (float*)lds;              // [128][33]  (16896 B)
    float* colm  = (float*)(lds + 16896);    // [128][9]   (4608 B)
    float* mrowS = (float*)(lds + 21504);    // [128]
    float* mcolS = (float*)(lds + 22016);    // [128]

    const int grp32 = wc * 16 + l15;
    const int grp8  = wr * 4 + (lane >> 4);
    int rloc[16], cloc[4];
    int rowlab[16], collab[4];
    #pragma unroll
    for (int rf = 0; rf < 4; ++rf)
        #pragma unroll
        for (int rg = 0; rg < 4; ++rg) {
            int i = rf * 4 + rg;
            rloc[i] = wr * 64 + rf * 16 + (lane >> 4) * 4 + rg;
            rowlab[i] = label[(rowBase + rloc[i]) & (N_ - 1)];
        }
    #pragma unroll
    for (int cf = 0; cf < 4; ++cf) {
        cloc[cf] = wc * 64 + cf * 16 + l15;
        collab[cf] = label[(colBase + cloc[cf]) & (N_ - 1)];
    }

    // masked log2-logits in place
    #pragma unroll
    for (int rf = 0; rf < 4; ++rf)
        #pragma unroll
        for (int cf = 0; cf < 4; ++cf)
            #pragma unroll
            for (int rg = 0; rg < 4; ++rg) {
                float v = acc[rf][cf][rg] * K_LOG2;
                acc[rf][cf][rg] = (collab[cf] == rowlab[rf * 4 + rg]) ? NEGINF : v;
            }

    // pass 1: maxes
    #pragma unroll
    for (int rf = 0; rf < 4; ++rf)
        #pragma unroll
        for (int rg = 0; rg < 4; ++rg) {
            float m = fmaxf(fmaxf(acc[rf][0][rg], acc[rf][1][rg]),
                            fmaxf(acc[rf][2][rg], acc[rf][3][rg]));
            rowm[rloc[rf * 4 + rg] * 33 + grp32] = m;
        }
    if (offdiag) {
        #pragma unroll
        for (int cf = 0; cf < 4; ++cf) {
            float m = NEGINF;
            #pragma unroll
            for (int rf = 0; rf < 4; ++rf)
                #pragma unroll
                for (int rg = 0; rg < 4; ++rg) m = fmaxf(m, acc[rf][cf][rg]);
            colm[cloc[cf] * 9 + grp8] = m;
        }
    }
    __syncthreads();
    if (tid < 128) {
        float m = NEGINF;
        #pragma unroll
        for (int g = 0; g < 32; ++g) m = fmaxf(m, rowm[tid * 33 + g]);
        mrowS[tid] = m;
        if (offdiag) {
            float mc = NEGINF;
            #pragma unroll
            for (int g = 0; g < 8; ++g) mc = fmaxf(mc, colm[tid * 9 + g]);
            mcolS[tid] = mc;
        }
    }
    __syncthreads();

    // pass 2: sums (reuse rowm/colm)
    #pragma unroll
    for (int rf = 0; rf < 4; ++rf)
        #pragma unroll
        for (int rg = 0; rg < 4; ++rg) {
            int i = rf * 4 + rg;
            float m = mrowS[rloc[i]];
            float s = 0.f;
            #pragma unroll
            for (int cf = 0; cf < 4; ++cf) s += exp2f(acc[rf][cf][rg] - m);
            rowm[rloc[i] * 33 + grp32] = s;
        }
    if (offdiag) {
        #pragma unroll
        for (int cf = 0; cf < 4; ++cf) {
            float m = mcolS[cloc[cf]];
            float s = 0.f;
            #pragma unroll
            for (int rf = 0; rf < 4; ++rf)
                #pragma unroll
                for (int rg = 0; rg < 4; ++rg) s += exp2f(acc[rf][cf][rg] - m);
            colm[cloc[cf] * 9 + grp8] = s;
        }
    }
    __syncthreads();
    if (tid < 128) {
        float s = 0.f;
        #pragma unroll
        for (int g = 0; g < 32; ++g) s += rowm[tid * 33 + g];
        partial[(size_t)(rowBase + tid) * 64 + ct] = make_float2(mrowS[tid], s);
        if (offdiag) {
            float s2 = 0.f;
            #pragma unroll
            for (int g = 0; g < 8; ++g) s2 += colm[tid * 9 + g];
            partial[(size_t)(colBase + tid) * 64 + rt] = make_float2(mcolS[tid], s2);
        }
    }
}

// ---------- Phase B: merge + group-parallel dots + CE + last-block final ----------
__global__ __launch_bounds__(512) void phaseB(const float* __restrict__ feat,
                                              const int* __restrict__ label,
                                              const int* __restrict__ camid,
                                              const int* __restrict__ lists,
                                              const float2* __restrict__ partial,
                                              float* __restrict__ rowloss,
                                              int* __restrict__ done,
                                              float* __restrict__ out) {
    __shared__ int   cList[8][64];
    __shared__ int   fList[8][64];
    __shared__ float pList[8][64];
    __shared__ float red[512];
    __shared__ int   lastFlag;

    const int tid = threadIdx.x, lane = tid & 63, w = tid >> 6;
    const int row = blockIdx.x * 8 + w;
    const int rl = label[row & (N_ - 1)];
    const int rc = camid[row & (N_ - 1)];

    // c_id: coalesced row-major partial + butterfly merge (log2 domain)
    float2 p = partial[(size_t)row * 64 + lane];
    float mm = p.x, ms = p.y;
    #pragma unroll
    for (int off = 32; off >= 1; off >>= 1) {
        float om = __shfl_xor(mm, off), os = __shfl_xor(ms, off);
        float nm = fmaxf(mm, om);
        ms = ms * exp2f(mm - nm) + os * exp2f(om - nm);
        mm = nm;
    }
    const float cid = (mm + __log2f(ms)) * LN2F;

    // own row slice: lane li=lane&15 covers floats [li*16, li*16+16)
    const int li = lane & 15, g = lane >> 4;
    const float4* fip = (const float4*)frow(feat, row);
    float4 fiv[4];
    #pragma unroll
    for (int k = 0; k < 4; ++k) fiv[k] = fip[li * 4 + k];

    // candidate compaction (ascending, deterministic)
    const int* Lp = lists + (size_t)rl * (LCAP + 1);
    const int nmem = Lp[0];
    int jm = (lane < 2 * nmem) ? Lp[1 + (lane >> 1)] : -1;
    int cand = jm + (lane & 1) * N_;
    bool valid = (jm >= 0) && (cand != row);
    unsigned long long mask = __ballot(valid);
    int cnt = __popcll(mask);
    int pos = __popcll(mask & ((1ull << lane) - 1ull));
    if (valid) {
        cList[w][pos] = cand;
        fList[w][pos] = (camid[jm] == rc) ? 1 : 0;
    }

    // group-parallel dots: 4 candidates per batch (16 lanes each)
    const int nb = (cnt + 3) >> 2;
    for (int b = 0; b < nb; ++b) {
        int e = b * 4 + g;
        bool act = (e < cnt);
        int c = act ? cList[w][e] : row;
        const float4* fcp = (const float4*)frow(feat, c);
        float pp = 0.f;
        #pragma unroll
        for (int k = 0; k < 4; ++k) {
            float4 v = fcp[li * 4 + k];
            pp += fiv[k].x * v.x + fiv[k].y * v.y + fiv[k].z * v.z + fiv[k].w * v.w;
        }
        #pragma unroll
        for (int off = 8; off >= 1; off >>= 1) pp += __shfl_xor(pp, off);
        if (act && li == 0) pList[w][e] = pp * INV_TEMP;
    }

    float a_e = (lane < cnt) ? pList[w][lane] : NEGINF;
    int   f_e = (lane < cnt) ? fList[w][lane] : 1;

    // extras LSE (label-match, cam-mismatch) -> c_cam
    float xa = (f_e == 0) ? a_e : NEGINF;
    float mx = xa;
    #pragma unroll
    for (int off = 32; off >= 1; off >>= 1) mx = fmaxf(mx, __shfl_xor(mx, off));
    float xe = (f_e == 0) ? __expf(xa - mx) : 0.f;
    #pragma unroll
    for (int off = 32; off >= 1; off >>= 1) xe += __shfl_xor(xe, off);
    float ccam;
    if (xe > 0.f) {
        float xl = mx + __logf(xe);
        float d = xl - cid;
        ccam = (d <= 0.f) ? cid + log1pf(__expf(d)) : xl + log1pf(__expf(-d));
    } else {
        ccam = cid;
    }

    float ti = cid - a_e;
    float termid = (ti <= 0.f) ? log1pf(__expf(ti)) : ti + log1pf(__expf(-ti));
    termid = (lane < cnt) ? termid : 0.f;
    float tc = ccam - a_e;
    float termcam = (tc <= 0.f) ? log1pf(__expf(tc)) : tc + log1pf(__expf(-tc));
    termcam = (lane < cnt && f_e) ? termcam : 0.f;
    #pragma unroll
    for (int off = 32; off >= 1; off >>= 1) {
        termid  += __shfl_xor(termid, off);
        termcam += __shfl_xor(termcam, off);
    }
    int ncam = __popcll(__ballot(lane < cnt && f_e));
    if (lane == 0)
        rowloss[row] = termid / (float)cnt + 0.5f * termcam / (float)ncam;

    // ---- last-block deterministic final reduce ----
    __syncthreads();
    if (tid == 0) {
        __threadfence();
        lastFlag = (atomicAdd(done, 1) == (int)gridDim.x - 1) ? 1 : 0;
    }
    __syncthreads();
    if (lastFlag) {
        __threadfence();
        float s = 0.f;
        const int b0 = tid * 16;
        #pragma unroll
        for (int i = 0; i < 16; ++i) s += rowloss[b0 + i];   // fixed order
        red[tid] = s;
        __syncthreads();
        for (int ww = 256; ww > 0; ww >>= 1) {
            if (tid < ww) red[tid] += red[tid + ww];
            __syncthreads();
        }
        if (tid == 0) out[0] = red[0] / (float)N2;
    }
}

extern "C" void kernel_launch(void* const* d_in, const int* in_sizes, int n_in,
                              void* d_out, int out_size, void* d_ws, size_t ws_size,
                              hipStream_t stream) {
    const float* feat  = (const float*)d_in[0];
    const int*   label = (const int*)d_in[1];
    const int*   camid = (const int*)d_in[2];

    float2* partial = (float2*)d_ws;                                 // 4 MB
    float*  rowloss = (float*)((char*)d_ws + 4u * 1024 * 1024);      // 32 KB
    int*    lists   = (int*)(rowloss + N2);                          // ~132 KB
    int*    done    = lists + NIDS * (LCAP + 1);                     // 4 B

    phaseA<<<2080, 256, 0, stream>>>(feat, label, partial, lists, done);
    phaseB<<<1024, 512, 0, stream>>>(feat, label, camid, lists, partial,
                                     rowloss, done, (float*)d_out);
}